// Round 6
// baseline (790.799 us; speedup 1.0000x reference)
//
#include <hip/hip_runtime.h>
#include <math.h>

#define N_TOK 131072
#define DIM 64
#define KCODES 1024
#define TPB 128         // tokens per block (main kernel): 4 waves x 2 sets x 16
#define TIE_EPS 1e-4f

typedef __attribute__((ext_vector_type(8))) short short8;
typedef __attribute__((ext_vector_type(4))) float float4v;

static __device__ inline unsigned short f2bf(float x) {
    unsigned u = __float_as_uint(x);
    unsigned r = (u + 0x7FFF + ((u >> 16) & 1)) >> 16;
    return (unsigned short)r;
}
static __device__ inline float bf2f(unsigned short b) {
    return __uint_as_float(((unsigned)b) << 16);
}

// ---------------- prep: normalized codebook -> bf16 hi/lo B-fragments, norms, zero counters
__global__ __launch_bounds__(64) void vq_prep(
    const float* __restrict__ w, unsigned short* __restrict__ bfrag_hi,
    unsigned short* __restrict__ bfrag_lo, double* __restrict__ inv_n64,
    float* __restrict__ nw, int* __restrict__ count, int* __restrict__ nflag,
    double* __restrict__ delta)
{
    int k = blockIdx.x;   // code
    int d = threadIdx.x;  // dim
    float v = w[k * DIM + d];
    float s = v * v;
    #pragma unroll
    for (int off = 32; off; off >>= 1) s += __shfl_xor(s, off);
    float den = fmaxf(sqrtf(s), 1e-12f);
    float nv = v / den;
    unsigned short hi = f2bf(nv);
    unsigned short lo = f2bf(nv - bf2f(hi));

    // B-fragment for mfma_f32_16x16x32_bf16: lane l holds B[n=l&15][kk=(l>>4)*8+j]
    int t  = k >> 4;          // code tile
    int nl = k & 15;
    int s2 = d >> 5;          // k-step
    int q  = (d >> 3) & 3;
    int j  = d & 7;
    int l  = nl + 16 * q;
    size_t pos = ((size_t)(t * 2 + s2) * 64 + l) * 8 + j;
    bfrag_hi[pos] = hi;
    bfrag_lo[pos] = lo;

    double vd = (double)v;
    double sd = vd * vd;
    #pragma unroll
    for (int off = 32; off; off >>= 1) sd += __shfl_xor(sd, off);
    if (d == 0) {
        inv_n64[k] = 1.0 / fmax(sqrt(sd), 1e-12);
        nw[k] = den;
    }
    if (k == 0) {
        for (int i = d; i < KCODES; i += 64) count[i] = 0;
        if (d == 0) { nflag[0] = 0; delta[0] = 0.0; }
    }
}

// ---------------- zero-fill of encodings: pure streaming stores (fillBuffer pattern)
__global__ __launch_bounds__(256) void vq_zero(float* __restrict__ enc)
{
    const size_t NF4 = ((size_t)N_TOK * KCODES - 4) / 4;   // 33554431 float4s from enc+2
    float4* p = (float4*)(enc + 2);
    const float4 z4 = {0.f, 0.f, 0.f, 0.f};
    size_t i = (size_t)blockIdx.x * 256 + threadIdx.x;
    const size_t stride = (size_t)gridDim.x * 256;
    for (size_t j = i; j < NF4; j += stride) p[j] = z4;
    if (i == 0) {
        enc[0] = 0.f; enc[1] = 0.f;
        enc[(size_t)N_TOK * KCODES - 2] = 0.f;
        enc[(size_t)N_TOK * KCODES - 1] = 0.f;
    }
}

static __device__ inline void merge3(float& b, float& s, int& i, float ob, float os, int oi) {
    if (ob > b) { s = fmaxf(b, os); b = ob; i = oi; }
    else if (ob == b) { s = b; if (oi < i) i = oi; }
    else { s = fmaxf(s, ob); }
}

// ---------------- main (lean): MFMA distance + argmax + loss partials. NO output streaming.
__global__ __launch_bounds__(256, 4) void vq_main(
    const float* __restrict__ inputs,
    const unsigned short* __restrict__ bfrag_hi, const unsigned short* __restrict__ bfrag_lo,
    const float* __restrict__ nw, int* __restrict__ g_idx, int* __restrict__ count,
    double* __restrict__ partial, int* __restrict__ nflag, int* __restrict__ flags)
{
    __shared__ float s_part[4];

    const int tid  = threadIdx.x;
    const int lane = tid & 63;
    const int wv   = tid >> 6;
    const int col  = lane & 15;
    const int quad = lane >> 4;
    const int n0   = blockIdx.x * TPB;

    // ---- A fragments straight from global (no LDS). 2 sets x 16 tokens per wave.
    short8 ah[2][2], al[2][2];
    float n2z[2];
    #pragma unroll
    for (int s = 0; s < 2; s++) {
        int m = n0 + wv * 32 + s * 16 + col;
        const float* zp = inputs + (size_t)m * DIM + quad * 8;
        float4 f0 = *(const float4*)zp;
        float4 f1 = *(const float4*)(zp + 4);
        float4 f2 = *(const float4*)(zp + 32);
        float4 f3 = *(const float4*)(zp + 36);
        float v[16] = {f0.x,f0.y,f0.z,f0.w, f1.x,f1.y,f1.z,f1.w,
                       f2.x,f2.y,f2.z,f2.w, f3.x,f3.y,f3.z,f3.w};
        float ss = 0.f;
        #pragma unroll
        for (int j = 0; j < 16; j++) ss += v[j] * v[j];
        ss += __shfl_xor(ss, 16);   // quad-reduction: lanes differing in bits 4..5
        ss += __shfl_xor(ss, 32);
        n2z[s] = ss;
        float inv = 1.0f / fmaxf(sqrtf(ss), 1e-12f);   // any per-token scale is argmax-safe
        #pragma unroll
        for (int j = 0; j < 8; j++) {
            float x0 = v[j] * inv;
            unsigned short h0 = f2bf(x0);
            ah[s][0][j] = (short)h0;
            al[s][0][j] = (short)f2bf(x0 - bf2f(h0));
            float x1 = v[8 + j] * inv;
            unsigned short h1 = f2bf(x1);
            ah[s][1][j] = (short)h1;
            al[s][1][j] = (short)f2bf(x1 - bf2f(h1));
        }
    }

    // ---- K loop over 64 code tiles with branch-free B prefetch
    float best[8], sec[8]; int bidx[8];
    #pragma unroll
    for (int i = 0; i < 8; i++) { best[i] = -1e30f; sec[i] = -1e30f; bidx[i] = 0x7fffffff; }

    const short8* bhp = (const short8*)bfrag_hi;
    const short8* blp = (const short8*)bfrag_lo;
    short8 c0h = bhp[lane], c1h = bhp[64 + lane];
    short8 c0l = blp[lane], c1l = blp[64 + lane];

    for (int t = 0; t < 64; t++) {
        int tn = (t < 63) ? (t + 1) : 63;       // tile 63 re-read, unused
        size_t o = (size_t)(2 * tn) * 64 + lane;
        short8 p0h = bhp[o], p1h = bhp[o + 64];
        short8 p0l = blp[o], p1l = blp[o + 64];

        float4v acc0 = {0.f,0.f,0.f,0.f}, acc1 = {0.f,0.f,0.f,0.f};
        acc0 = __builtin_amdgcn_mfma_f32_16x16x32_bf16(ah[0][0], c0h, acc0, 0,0,0);
        acc1 = __builtin_amdgcn_mfma_f32_16x16x32_bf16(ah[1][0], c0h, acc1, 0,0,0);
        acc0 = __builtin_amdgcn_mfma_f32_16x16x32_bf16(al[0][0], c0h, acc0, 0,0,0);
        acc1 = __builtin_amdgcn_mfma_f32_16x16x32_bf16(al[1][0], c0h, acc1, 0,0,0);
        acc0 = __builtin_amdgcn_mfma_f32_16x16x32_bf16(ah[0][0], c0l, acc0, 0,0,0);
        acc1 = __builtin_amdgcn_mfma_f32_16x16x32_bf16(ah[1][0], c0l, acc1, 0,0,0);
        acc0 = __builtin_amdgcn_mfma_f32_16x16x32_bf16(ah[0][1], c1h, acc0, 0,0,0);
        acc1 = __builtin_amdgcn_mfma_f32_16x16x32_bf16(ah[1][1], c1h, acc1, 0,0,0);
        acc0 = __builtin_amdgcn_mfma_f32_16x16x32_bf16(al[0][1], c1h, acc0, 0,0,0);
        acc1 = __builtin_amdgcn_mfma_f32_16x16x32_bf16(al[1][1], c1h, acc1, 0,0,0);
        acc0 = __builtin_amdgcn_mfma_f32_16x16x32_bf16(ah[0][1], c1l, acc0, 0,0,0);
        acc1 = __builtin_amdgcn_mfma_f32_16x16x32_bf16(ah[1][1], c1l, acc1, 0,0,0);

        int k = t * 16 + col;
        #pragma unroll
        for (int i = 0; i < 4; i++) {
            float v0 = acc0[i];
            sec[i]  = __builtin_amdgcn_fmed3f(best[i], sec[i], v0);
            bool g0 = v0 > best[i];
            best[i] = fmaxf(best[i], v0);
            bidx[i] = g0 ? k : bidx[i];
            float v1 = acc1[i];
            sec[4+i]  = __builtin_amdgcn_fmed3f(best[4+i], sec[4+i], v1);
            bool g1 = v1 > best[4 + i];
            best[4 + i] = fmaxf(best[4 + i], v1);
            bidx[4 + i] = g1 ? k : bidx[4 + i];
        }
        c0h = p0h; c1h = p1h; c0l = p0l; c1l = p1l;
    }

    // ---- cross-lane argmax over the 16 code-columns
    #pragma unroll
    for (int off = 1; off < 16; off <<= 1) {
        #pragma unroll
        for (int i = 0; i < 8; i++) {
            float ob = __shfl_xor(best[i], off);
            float os = __shfl_xor(sec[i], off);
            int   oi = __shfl_xor(bidx[i], off);
            merge3(best[i], sec[i], bidx[i], ob, os, oi);
        }
    }

    // ---- per-token bookkeeping at col==0 lanes; loss via |z|^2 - 2 cos |z||w| + |w|^2
    float lsum = 0.f;
    #pragma unroll
    for (int s = 0; s < 2; s++) {
        #pragma unroll
        for (int i = 0; i < 4; i++) {
            int r = s * 4 + i;
            float n2 = __shfl(n2z[s], quad * 4 + i);   // all lanes participate
            if (col == 0) {
                int tl = wv * 32 + s * 16 + quad * 4 + i;
                int k  = bidx[r];
                g_idx[n0 + tl] = k;
                atomicAdd(&count[k], 1);
                if (best[r] - sec[r] < TIE_EPS) {
                    int p = atomicAdd(nflag, 1);
                    flags[p] = n0 + tl;
                }
                float nwk = nw[k];
                float zw  = best[r] * sqrtf(n2) * nwk;
                lsum += n2 - 2.f * zw + nwk * nwk;
            }
        }
    }
    lsum += __shfl_xor(lsum, 16);
    lsum += __shfl_xor(lsum, 32);
    if (lane == 0) s_part[wv] = lsum;
    __syncthreads();
    if (tid == 0)
        partial[blockIdx.x] = (double)(s_part[0] + s_part[1] + s_part[2] + s_part[3]);
}

// ---------------- scatter: quantized rows (coalesced) + one-hot 1.0 stores
__global__ __launch_bounds__(256) void vq_scatter(
    const float* __restrict__ w, const int* __restrict__ g_idx,
    float* __restrict__ out_q, float* __restrict__ out_enc)
{
    int g  = blockIdx.x * 256 + threadIdx.x;   // float4 id over [N][16]
    int n  = g >> 4;
    int d4 = (g & 15) * 4;
    int k  = g_idx[n];
    float4 q = *(const float4*)&w[(size_t)k * DIM + d4];
    size_t ob = (size_t)n * DIM + d4;          // out_q base is d_out+1 (4B-aligned) -> scalar stores
    out_q[ob + 0] = q.x; out_q[ob + 1] = q.y; out_q[ob + 2] = q.z; out_q[ob + 3] = q.w;
    if ((g & 15) == 0) out_enc[(size_t)n * KCODES + k] = 1.0f;
}

// ---------------- rescan: fp64 exact argmin for near-tie tokens; patch outputs
__global__ __launch_bounds__(64) void vq_rescan(
    const float* __restrict__ inputs, const float* __restrict__ w,
    const double* __restrict__ inv_n64, const int* __restrict__ g_idx,
    const int* __restrict__ flags, const int* __restrict__ nflag,
    int* __restrict__ count, float* __restrict__ out_q,
    float* __restrict__ out_enc, double* __restrict__ delta)
{
    __shared__ double sz[64];
    int lane = threadIdx.x;
    int nf = nflag[0];
    for (int i = blockIdx.x; i < nf; i += gridDim.x) {
        int tok = flags[i];
        double zd = (double)inputs[(size_t)tok * DIM + lane];
        double ss = zd * zd;
        #pragma unroll
        for (int off = 32; off; off >>= 1) ss += __shfl_xor(ss, off);
        sz[lane] = zd / fmax(sqrt(ss), 1e-12);
        __syncthreads();
        double bv = -1e300; int bi = 0x7fffffff;
        for (int c = 0; c < 16; c++) {
            int k = c * 64 + lane;
            double invk = inv_n64[k];
            double dot = 0.0;
            #pragma unroll 8
            for (int d = 0; d < DIM; d++)
                dot += sz[d] * ((double)w[(size_t)k * DIM + d] * invk);
            if (dot > bv) { bv = dot; bi = k; }
        }
        #pragma unroll
        for (int off = 1; off < 64; off <<= 1) {
            double ov = __shfl_xor(bv, off);
            int   oi = __shfl_xor(bi, off);
            if (ov > bv || (ov == bv && oi < bi)) { bv = ov; bi = oi; }
        }
        int kold = g_idx[tok];
        if (bi != kold) {
            double wn = (double)w[(size_t)bi * DIM + lane];
            double wo = (double)w[(size_t)kold * DIM + lane];
            double zr = (double)inputs[(size_t)tok * DIM + lane];
            double a = wn * wn - wo * wo - 2.0 * zr * (wn - wo);
            #pragma unroll
            for (int off = 32; off; off >>= 1) a += __shfl_xor(a, off);
            out_q[(size_t)tok * DIM + lane] = (float)wn;
            if (lane == 0) {
                atomicAdd(&count[kold], -1);
                atomicAdd(&count[bi], 1);
                out_enc[(size_t)tok * KCODES + kold] = 0.f;
                out_enc[(size_t)tok * KCODES + bi]   = 1.f;
                atomicAdd(delta, a);
            }
        }
        __syncthreads();
    }
}

// ---------------- finalize: loss scalar + perplexity
__global__ __launch_bounds__(256) void vq_final(
    const int* __restrict__ count, const double* __restrict__ partial,
    const double* __restrict__ delta, float* __restrict__ out_loss,
    float* __restrict__ out_perp)
{
    __shared__ double s1[256], s2[256];
    int tid = threadIdx.x;
    double lp = 0.0, ls = 0.0;
    for (int k = tid; k < KCODES; k += 256) {
        double p = (double)count[k] / (double)N_TOK;
        lp += p * log(p + 1e-10);
    }
    for (int i = tid; i < 1024; i += 256) ls += partial[i];
    s1[tid] = lp; s2[tid] = ls;
    __syncthreads();
    for (int st = 128; st; st >>= 1) {
        if (tid < st) { s1[tid] += s1[tid + st]; s2[tid] += s2[tid + st]; }
        __syncthreads();
    }
    if (tid == 0) {
        out_perp[0] = (float)exp(-s1[0]);
        out_loss[0] = (float)(1.25 * (s2[0] + delta[0]) / ((double)N_TOK * (double)DIM));
    }
}

extern "C" void kernel_launch(void* const* d_in, const int* in_sizes, int n_in,
                              void* d_out, int out_size, void* d_ws, size_t ws_size,
                              hipStream_t stream) {
    const float* inputs = (const float*)d_in[0];
    const float* weight = (const float*)d_in[1];
    float* out      = (float*)d_out;
    float* out_loss = out;                               // [1]
    float* out_q    = out + 1;                           // [N*D]
    float* out_perp = out + 1 + (size_t)N_TOK * DIM;     // [1]
    float* out_enc  = out_perp + 1;                      // [N*K], 8B-aligned

    char* ws = (char*)d_ws;
    unsigned short* bfrag_hi = (unsigned short*)ws;                  // 131072 B
    unsigned short* bfrag_lo = (unsigned short*)(ws + 131072);       // 131072 B
    double* inv_n64 = (double*)(ws + 262144);                        // 8192 B
    float*  nw      = (float*)(ws + 270336);                         // 4096 B
    int*    g_idx   = (int*)(ws + 274432);                           // 524288 B
    int*    count   = (int*)(ws + 798720);                           // 4096 B
    double* partial = (double*)(ws + 802816);                        // 8192 B
    double* delta   = (double*)(ws + 811008);                        // 8 B
    int*    nflag   = (int*)(ws + 811016);                           // 4 B
    int*    flags   = (int*)(ws + 811020);                           // 524288 B

    vq_prep<<<KCODES, 64, 0, stream>>>(weight, bfrag_hi, bfrag_lo, inv_n64, nw,
                                       count, nflag, delta);
    vq_zero<<<2048, 256, 0, stream>>>(out_enc);
    vq_main<<<N_TOK / TPB, 256, 0, stream>>>(inputs, bfrag_hi, bfrag_lo, nw,
                                             g_idx, count, partial, nflag, flags);
    vq_scatter<<<(N_TOK * 16) / 256, 256, 0, stream>>>(weight, g_idx, out_q, out_enc);
    vq_rescan<<<256, 64, 0, stream>>>(inputs, weight, inv_n64, g_idx, flags, nflag,
                                      count, out_q, out_enc, delta);
    vq_final<<<1, 256, 0, stream>>>(count, partial, delta, out_loss, out_perp);
}

// Round 7
// 675.297 us; speedup vs baseline: 1.1710x; 1.1710x over previous
//
#include <hip/hip_runtime.h>
#include <math.h>

#define N_TOK 131072
#define DIM 64
#define KCODES 1024
#define TPB 128         // tokens per block (main kernel): 4 waves x 2 sets x 16
#define TIE_EPS 1e-4f

typedef __attribute__((ext_vector_type(8))) short short8;
typedef __attribute__((ext_vector_type(4))) float float4v;

static __device__ inline unsigned short f2bf(float x) {
    unsigned u = __float_as_uint(x);
    unsigned r = (u + 0x7FFF + ((u >> 16) & 1)) >> 16;
    return (unsigned short)r;
}
static __device__ inline float bf2f(unsigned short b) {
    return __uint_as_float(((unsigned)b) << 16);
}

// ---------------- prep: normalized codebook -> bf16 hi/lo B-fragments, norms, zero counters
__global__ __launch_bounds__(64) void vq_prep(
    const float* __restrict__ w, unsigned short* __restrict__ bfrag_hi,
    unsigned short* __restrict__ bfrag_lo, double* __restrict__ inv_n64,
    float* __restrict__ nw, int* __restrict__ count, int* __restrict__ nflag,
    double* __restrict__ delta)
{
    int k = blockIdx.x;   // code
    int d = threadIdx.x;  // dim
    float v = w[k * DIM + d];
    float s = v * v;
    #pragma unroll
    for (int off = 32; off; off >>= 1) s += __shfl_xor(s, off);
    float den = fmaxf(sqrtf(s), 1e-12f);
    float nv = v / den;
    unsigned short hi = f2bf(nv);
    unsigned short lo = f2bf(nv - bf2f(hi));

    // B-fragment for mfma_f32_16x16x32_bf16: lane l holds B[n=l&15][kk=(l>>4)*8+j]
    int t  = k >> 4;          // code tile
    int nl = k & 15;
    int s2 = d >> 5;          // k-step
    int q  = (d >> 3) & 3;
    int j  = d & 7;
    int l  = nl + 16 * q;
    size_t pos = ((size_t)(t * 2 + s2) * 64 + l) * 8 + j;
    bfrag_hi[pos] = hi;
    bfrag_lo[pos] = lo;

    double vd = (double)v;
    double sd = vd * vd;
    #pragma unroll
    for (int off = 32; off; off >>= 1) sd += __shfl_xor(sd, off);
    if (d == 0) {
        inv_n64[k] = 1.0 / fmax(sqrt(sd), 1e-12);
        nw[k] = den;
    }
    if (k == 0) {
        for (int i = d; i < KCODES; i += 64) count[i] = 0;
        if (d == 0) { nflag[0] = 0; delta[0] = 0.0; }
    }
}

static __device__ inline void merge3(float& b, float& s, int& i, float ob, float os, int oi) {
    if (ob > b) { s = fmaxf(b, os); b = ob; i = oi; }
    else if (ob == b) { s = b; if (oi < i) i = oi; }
    else { s = fmaxf(s, ob); }
}

// ---------------- main: MFMA distance + argmax + burst/interleaved enc zero-fill + fused epilogue
__global__ __launch_bounds__(256, 4) void vq_main(
    const float* __restrict__ inputs, const float* __restrict__ w,
    const unsigned short* __restrict__ bfrag_hi, const unsigned short* __restrict__ bfrag_lo,
    const float* __restrict__ nw, int* __restrict__ g_idx, int* __restrict__ count,
    double* __restrict__ partial, int* __restrict__ nflag, int* __restrict__ flags,
    float* __restrict__ out_q, float* __restrict__ out_enc)
{
    __shared__ int   s_idx[TPB];
    __shared__ float s_part[4];

    const int tid  = threadIdx.x;
    const int lane = tid & 63;
    const int wv   = tid >> 6;
    const int col  = lane & 15;
    const int quad = lane >> 4;
    const int n0   = blockIdx.x * TPB;

    // ---- issue A loads first (oldest vm ops -> normalize's vmcnt wait skips the burst stores)
    float4 f[2][4];
    #pragma unroll
    for (int s = 0; s < 2; s++) {
        int m = n0 + wv * 32 + s * 16 + col;
        const float* zp = inputs + (size_t)m * DIM + quad * 8;
        f[s][0] = *(const float4*)zp;
        f[s][1] = *(const float4*)(zp + 4);
        f[s][2] = *(const float4*)(zp + 32);
        f[s][3] = *(const float4*)(zp + 36);
    }

    // ---- entry burst: 32 zero float4s per thread (1/4 of this block's enc span),
    // fire-and-forget while the A loads are still in flight.
    float* enc0 = out_enc + (size_t)n0 * KCODES;   // out_enc is 8B-aligned; +2 is 16B-aligned
    const float4 zero4 = {0.f, 0.f, 0.f, 0.f};
    #pragma unroll 8
    for (int i = 0; i < 32; i++) {
        int p = i * 256 + tid;                     // p <= 8191 here, no overrun
        *(float4*)(enc0 + 2 + 4 * (size_t)p) = zero4;
    }

    // ---- normalize + build A fragments (hi/lo split)
    short8 ah[2][2], al[2][2];
    float n2z[2];
    #pragma unroll
    for (int s = 0; s < 2; s++) {
        float v[16] = {f[s][0].x,f[s][0].y,f[s][0].z,f[s][0].w,
                       f[s][1].x,f[s][1].y,f[s][1].z,f[s][1].w,
                       f[s][2].x,f[s][2].y,f[s][2].z,f[s][2].w,
                       f[s][3].x,f[s][3].y,f[s][3].z,f[s][3].w};
        float ss = 0.f;
        #pragma unroll
        for (int j = 0; j < 16; j++) ss += v[j] * v[j];
        ss += __shfl_xor(ss, 16);   // quad-reduction: lanes differing in bits 4..5
        ss += __shfl_xor(ss, 32);
        n2z[s] = ss;
        float inv = 1.0f / fmaxf(sqrtf(ss), 1e-12f);   // per-token scale is argmax-safe
        #pragma unroll
        for (int j = 0; j < 8; j++) {
            float x0 = v[j] * inv;
            unsigned short h0 = f2bf(x0);
            ah[s][0][j] = (short)h0;
            al[s][0][j] = (short)f2bf(x0 - bf2f(h0));
            float x1 = v[8 + j] * inv;
            unsigned short h1 = f2bf(x1);
            ah[s][1][j] = (short)h1;
            al[s][1][j] = (short)f2bf(x1 - bf2f(h1));
        }
    }

    // ---- K loop over 64 code tiles; branch-free B prefetch + 2 zero stores/iter (t<48)
    float best[8], sec[8]; int bidx[8];
    #pragma unroll
    for (int i = 0; i < 8; i++) { best[i] = -1e30f; sec[i] = -1e30f; bidx[i] = 0x7fffffff; }

    const short8* bhp = (const short8*)bfrag_hi;
    const short8* blp = (const short8*)bfrag_lo;
    short8 c0h = bhp[lane], c1h = bhp[64 + lane];
    short8 c0l = blp[lane], c1l = blp[64 + lane];

    float* zp4 = enc0 + 2 + (size_t)(32 * 256 + tid) * 4;   // resume at i = 32

    for (int t = 0; t < 64; t++) {
        int tn = (t < 63) ? (t + 1) : 63;       // tile 63 re-read, unused
        size_t o = (size_t)(2 * tn) * 64 + lane;
        short8 p0h = bhp[o], p1h = bhp[o + 64];
        short8 p0l = blp[o], p1l = blp[o + 64];

        if (t < 48) {                            // i = 32+2t, 33+2t  (i max 127)
            int p = (32 + 2 * t) * 256 + tid;
            *(float4*)zp4 = zero4;
            if (p + 256 < 32767) *(float4*)(zp4 + KCODES) = zero4;   // skip final overrun slot
            zp4 += 2 * KCODES;
        }

        float4v acc0 = {0.f,0.f,0.f,0.f}, acc1 = {0.f,0.f,0.f,0.f};
        acc0 = __builtin_amdgcn_mfma_f32_16x16x32_bf16(ah[0][0], c0h, acc0, 0,0,0);
        acc1 = __builtin_amdgcn_mfma_f32_16x16x32_bf16(ah[1][0], c0h, acc1, 0,0,0);
        acc0 = __builtin_amdgcn_mfma_f32_16x16x32_bf16(al[0][0], c0h, acc0, 0,0,0);
        acc1 = __builtin_amdgcn_mfma_f32_16x16x32_bf16(al[1][0], c0h, acc1, 0,0,0);
        acc0 = __builtin_amdgcn_mfma_f32_16x16x32_bf16(ah[0][0], c0l, acc0, 0,0,0);
        acc1 = __builtin_amdgcn_mfma_f32_16x16x32_bf16(ah[1][0], c0l, acc1, 0,0,0);
        acc0 = __builtin_amdgcn_mfma_f32_16x16x32_bf16(ah[0][1], c1h, acc0, 0,0,0);
        acc1 = __builtin_amdgcn_mfma_f32_16x16x32_bf16(ah[1][1], c1h, acc1, 0,0,0);
        acc0 = __builtin_amdgcn_mfma_f32_16x16x32_bf16(al[0][1], c1h, acc0, 0,0,0);
        acc1 = __builtin_amdgcn_mfma_f32_16x16x32_bf16(al[1][1], c1h, acc1, 0,0,0);
        acc0 = __builtin_amdgcn_mfma_f32_16x16x32_bf16(ah[0][1], c1l, acc0, 0,0,0);
        acc1 = __builtin_amdgcn_mfma_f32_16x16x32_bf16(ah[1][1], c1l, acc1, 0,0,0);

        int k = t * 16 + col;
        #pragma unroll
        for (int i = 0; i < 4; i++) {
            float v0 = acc0[i];
            sec[i]  = __builtin_amdgcn_fmed3f(best[i], sec[i], v0);
            bool g0 = v0 > best[i];
            best[i] = fmaxf(best[i], v0);
            bidx[i] = g0 ? k : bidx[i];
            float v1 = acc1[i];
            sec[4+i]  = __builtin_amdgcn_fmed3f(best[4+i], sec[4+i], v1);
            bool g1 = v1 > best[4 + i];
            best[4 + i] = fmaxf(best[4 + i], v1);
            bidx[4 + i] = g1 ? k : bidx[4 + i];
        }
        c0h = p0h; c1h = p1h; c0l = p0l; c1l = p1l;
    }

    // ---- zero-fill edges (first/last 2 floats of span + the slot skipped above)
    if (tid == 0) {
        *(float2*)enc0 = make_float2(0.f, 0.f);
        *(float2*)(enc0 + (size_t)TPB * KCODES - 2) = make_float2(0.f, 0.f);
    }
    if (tid == 255) {    // p = 32767 float4 (last 4 floats before span end-2): zero as scalars
        float* q = enc0 + 2 + (size_t)32767 * 4;
        q[0] = 0.f; q[1] = 0.f; q[2] = 0.f; q[3] = 0.f;
    }

    // ---- cross-lane argmax over the 16 code-columns
    #pragma unroll
    for (int off = 1; off < 16; off <<= 1) {
        #pragma unroll
        for (int i = 0; i < 8; i++) {
            float ob = __shfl_xor(best[i], off);
            float os = __shfl_xor(sec[i], off);
            int   oi = __shfl_xor(bidx[i], off);
            merge3(best[i], sec[i], bidx[i], ob, os, oi);
        }
    }

    // ---- per-token bookkeeping at col==0 lanes; loss via |z|^2 - 2 cos |z||w| + |w|^2
    float lsum = 0.f;
    #pragma unroll
    for (int s = 0; s < 2; s++) {
        #pragma unroll
        for (int i = 0; i < 4; i++) {
            int r = s * 4 + i;
            float n2 = __shfl(n2z[s], quad * 4 + i);   // all lanes participate
            if (col == 0) {
                int tl = wv * 32 + s * 16 + quad * 4 + i;
                int k  = bidx[r];
                s_idx[tl] = k;
                g_idx[n0 + tl] = k;
                atomicAdd(&count[k], 1);
                if (best[r] - sec[r] < TIE_EPS) {
                    int p = atomicAdd(nflag, 1);
                    flags[p] = n0 + tl;
                }
                float nwk = nw[k];
                float zw  = best[r] * sqrtf(n2) * nwk;
                lsum += n2 - 2.f * zw + nwk * nwk;
            }
        }
    }
    lsum += __shfl_xor(lsum, 16);
    lsum += __shfl_xor(lsum, 32);
    if (lane == 0) s_part[wv] = lsum;
    __syncthreads();   // compiler drains vmcnt here: zero stores ordered before 1.0f stores
    if (tid == 0)
        partial[blockIdx.x] = (double)(s_part[0] + s_part[1] + s_part[2] + s_part[3]);

    // ---- epilogue: one-hot 1.0 stores + quantized rows (coalesced, L2-hot codebook gather)
    if (tid < TPB)
        out_enc[(size_t)(n0 + tid) * KCODES + s_idx[tid]] = 1.0f;

    const size_t qbase = (size_t)n0 * DIM;
    #pragma unroll 4
    for (int i2 = 0; i2 < 32; i2++) {
        int p = i2 * 256 + tid;
        int r = p >> 6, c = p & 63;
        int k = s_idx[r];
        out_q[qbase + p] = w[(size_t)k * DIM + c];
    }
}

// ---------------- rescan: fp64 exact argmin for near-tie tokens; patch outputs
// 2048 blocks + 4-way unrolled fp64 chains: ~0.5 us/token, scales to nf ~ 20K cheaply.
__global__ __launch_bounds__(64) void vq_rescan(
    const float* __restrict__ inputs, const float* __restrict__ w,
    const double* __restrict__ inv_n64, const int* __restrict__ g_idx,
    const int* __restrict__ flags, const int* __restrict__ nflag,
    int* __restrict__ count, float* __restrict__ out_q,
    float* __restrict__ out_enc, double* __restrict__ delta)
{
    __shared__ double sz[64];
    int lane = threadIdx.x;
    int nf = nflag[0];
    for (int i = blockIdx.x; i < nf; i += gridDim.x) {
        int tok = flags[i];
        double zd = (double)inputs[(size_t)tok * DIM + lane];
        double ss = zd * zd;
        #pragma unroll
        for (int off = 32; off; off >>= 1) ss += __shfl_xor(ss, off);
        sz[lane] = zd / fmax(sqrt(ss), 1e-12);
        __syncthreads();
        double bv = -1e300; int bi = 0x7fffffff;
        for (int c = 0; c < 16; c++) {
            int k = c * 64 + lane;
            double invk = inv_n64[k];
            const float* wr = w + (size_t)k * DIM;
            double d0 = 0.0, d1 = 0.0, d2 = 0.0, d3 = 0.0;
            #pragma unroll
            for (int d = 0; d < DIM; d += 4) {
                d0 += sz[d + 0] * ((double)wr[d + 0] * invk);
                d1 += sz[d + 1] * ((double)wr[d + 1] * invk);
                d2 += sz[d + 2] * ((double)wr[d + 2] * invk);
                d3 += sz[d + 3] * ((double)wr[d + 3] * invk);
            }
            double dot = (d0 + d1) + (d2 + d3);
            if (dot > bv) { bv = dot; bi = k; }
        }
        #pragma unroll
        for (int off = 1; off < 64; off <<= 1) {
            double ov = __shfl_xor(bv, off);
            int   oi = __shfl_xor(bi, off);
            if (ov > bv || (ov == bv && oi < bi)) { bv = ov; bi = oi; }
        }
        int kold = g_idx[tok];
        if (bi != kold) {
            double wn = (double)w[(size_t)bi * DIM + lane];
            double wo = (double)w[(size_t)kold * DIM + lane];
            double zr = (double)inputs[(size_t)tok * DIM + lane];
            double a = wn * wn - wo * wo - 2.0 * zr * (wn - wo);
            #pragma unroll
            for (int off = 32; off; off >>= 1) a += __shfl_xor(a, off);
            out_q[(size_t)tok * DIM + lane] = (float)wn;
            if (lane == 0) {
                atomicAdd(&count[kold], -1);
                atomicAdd(&count[bi], 1);
                out_enc[(size_t)tok * KCODES + kold] = 0.f;
                out_enc[(size_t)tok * KCODES + bi]   = 1.f;
                atomicAdd(delta, a);
            }
        }
        __syncthreads();
    }
}

// ---------------- finalize: loss scalar + perplexity
__global__ __launch_bounds__(256) void vq_final(
    const int* __restrict__ count, const double* __restrict__ partial,
    const double* __restrict__ delta, float* __restrict__ out_loss,
    float* __restrict__ out_perp)
{
    __shared__ double s1[256], s2[256];
    int tid = threadIdx.x;
    double lp = 0.0, ls = 0.0;
    for (int k = tid; k < KCODES; k += 256) {
        double p = (double)count[k] / (double)N_TOK;
        lp += p * log(p + 1e-10);
    }
    for (int i = tid; i < 1024; i += 256) ls += partial[i];
    s1[tid] = lp; s2[tid] = ls;
    __syncthreads();
    for (int st = 128; st; st >>= 1) {
        if (tid < st) { s1[tid] += s1[tid + st]; s2[tid] += s2[tid + st]; }
        __syncthreads();
    }
    if (tid == 0) {
        out_perp[0] = (float)exp(-s1[0]);
        out_loss[0] = (float)(1.25 * (s2[0] + delta[0]) / ((double)N_TOK * (double)DIM));
    }
}

extern "C" void kernel_launch(void* const* d_in, const int* in_sizes, int n_in,
                              void* d_out, int out_size, void* d_ws, size_t ws_size,
                              hipStream_t stream) {
    const float* inputs = (const float*)d_in[0];
    const float* weight = (const float*)d_in[1];
    float* out      = (float*)d_out;
    float* out_loss = out;                               // [1]
    float* out_q    = out + 1;                           // [N*D]
    float* out_perp = out + 1 + (size_t)N_TOK * DIM;     // [1]
    float* out_enc  = out_perp + 1;                      // [N*K], 8B-aligned

    char* ws = (char*)d_ws;
    unsigned short* bfrag_hi = (unsigned short*)ws;                  // 131072 B
    unsigned short* bfrag_lo = (unsigned short*)(ws + 131072);       // 131072 B
    double* inv_n64 = (double*)(ws + 262144);                        // 8192 B
    float*  nw      = (float*)(ws + 270336);                         // 4096 B
    int*    g_idx   = (int*)(ws + 274432);                           // 524288 B
    int*    count   = (int*)(ws + 798720);                           // 4096 B
    double* partial = (double*)(ws + 802816);                        // 8192 B
    double* delta   = (double*)(ws + 811008);                        // 8 B
    int*    nflag   = (int*)(ws + 811016);                           // 4 B
    int*    flags   = (int*)(ws + 811020);                           // 524288 B

    vq_prep<<<KCODES, 64, 0, stream>>>(weight, bfrag_hi, bfrag_lo, inv_n64, nw,
                                       count, nflag, delta);
    vq_main<<<N_TOK / TPB, 256, 0, stream>>>(inputs, weight, bfrag_hi, bfrag_lo, nw,
                                             g_idx, count, partial, nflag, flags,
                                             out_q, out_enc);
    vq_rescan<<<2048, 64, 0, stream>>>(inputs, weight, inv_n64, g_idx, flags, nflag,
                                       count, out_q, out_enc, delta);
    vq_final<<<1, 256, 0, stream>>>(count, partial, delta, out_loss, out_perp);
}